// Round 14
// baseline (157.261 us; speedup 1.0000x reference)
//
#include <hip/hip_runtime.h>

// h[v] = sum_{(u,v) in E} feat[u], feat: [N=100000,64] f32, E=1.2M.
// Round 14: ABLATION 2. r13 showed sort=6us, loop=47us (V2==V0). Loop cost
// is invariant to bytes, lines, lanes, occupancy -> discriminate between
// (a) random-access latency/service vs (b) loop codegen/issue overhead:
//   V3 = same loop, loads hit block-local 32KB (L1/L2 resident)
//   V4 = same loop, feat load replaced by VALU values (no global load)
//   V2 = same loop, random rows (47us replication)
//   V0 = real kernel, runs LAST (writes every output element).

#define NBKT_BITS 7
#define NODES_PER_BKT 128      // 1 << NBKT_BITS
#define NBKT_CAP 1024
#define BIN_CHUNK 4096
#define SRC_MASK 0x1FFFF       // 17 bits, N=100000 < 131072
#define EDGE_CAP 2048          // per-bucket capacity; mean 1534, 13-sigma margin

// ---------- LDS-aggregated direct-slot bin (int4 reads) ----------
__global__ __launch_bounds__(1024) void bin_direct_kernel(
        const int* __restrict__ src, const int* __restrict__ dst,
        int* __restrict__ bcnt, int* __restrict__ binned, int E, int NB) {
    __shared__ int cnt[NBKT_CAP];
    __shared__ int base[NBKT_CAP];
    const int beg = blockIdx.x * BIN_CHUNK;
    const int end = min(E, beg + BIN_CHUNK);
    const int nE = end - beg;
    for (int i = threadIdx.x; i < NB; i += blockDim.x) cnt[i] = 0;
    __syncthreads();
    if ((nE & 3) == 0) {
        const int nv = nE >> 2;
        for (int i = threadIdx.x; i < nv; i += blockDim.x) {
            const int4 d4 = *reinterpret_cast<const int4*>(dst + beg + i * 4);
            atomicAdd(&cnt[d4.x >> NBKT_BITS], 1);
            atomicAdd(&cnt[d4.y >> NBKT_BITS], 1);
            atomicAdd(&cnt[d4.z >> NBKT_BITS], 1);
            atomicAdd(&cnt[d4.w >> NBKT_BITS], 1);
        }
    } else {
        for (int i = beg + threadIdx.x; i < end; i += blockDim.x)
            atomicAdd(&cnt[dst[i] >> NBKT_BITS], 1);
    }
    __syncthreads();
    for (int i = threadIdx.x; i < NB; i += blockDim.x) {
        const int c = cnt[i];
        base[i] = c ? atomicAdd(&bcnt[i], c) : 0;
        cnt[i] = 0;
    }
    __syncthreads();
    if ((nE & 3) == 0) {
        const int nv = nE >> 2;
        for (int i = threadIdx.x; i < nv; i += blockDim.x) {
            const int4 d4 = *reinterpret_cast<const int4*>(dst + beg + i * 4);
            const int4 s4 = *reinterpret_cast<const int4*>(src + beg + i * 4);
            {
                const int b = d4.x >> NBKT_BITS;
                const int r = atomicAdd(&cnt[b], 1);
                const int pos = base[b] + r;
                if (pos < EDGE_CAP)
                    binned[(size_t)b * EDGE_CAP + pos] = s4.x | ((d4.x & (NODES_PER_BKT - 1)) << 17);
            }
            {
                const int b = d4.y >> NBKT_BITS;
                const int r = atomicAdd(&cnt[b], 1);
                const int pos = base[b] + r;
                if (pos < EDGE_CAP)
                    binned[(size_t)b * EDGE_CAP + pos] = s4.y | ((d4.y & (NODES_PER_BKT - 1)) << 17);
            }
            {
                const int b = d4.z >> NBKT_BITS;
                const int r = atomicAdd(&cnt[b], 1);
                const int pos = base[b] + r;
                if (pos < EDGE_CAP)
                    binned[(size_t)b * EDGE_CAP + pos] = s4.z | ((d4.z & (NODES_PER_BKT - 1)) << 17);
            }
            {
                const int b = d4.w >> NBKT_BITS;
                const int r = atomicAdd(&cnt[b], 1);
                const int pos = base[b] + r;
                if (pos < EDGE_CAP)
                    binned[(size_t)b * EDGE_CAP + pos] = s4.w | ((d4.w & (NODES_PER_BKT - 1)) << 17);
            }
        }
    } else {
        for (int i = beg + threadIdx.x; i < end; i += blockDim.x) {
            const int d = dst[i];
            const int b = d >> NBKT_BITS;
            const int r = atomicAdd(&cnt[b], 1);
            const int pos = base[b] + r;
            if (pos < EDGE_CAP)
                binned[(size_t)b * EDGE_CAP + pos] = src[i] | ((d & (NODES_PER_BKT - 1)) << 17);
        }
    }
}

// ---------- ablation gather ----------
// MODE 0 = full real kernel
// MODE 2 = loop-only, random rows (hashed)
// MODE 3 = loop-only, block-local rows (32KB working set, L1/L2-hit)
// MODE 4 = loop-only, NO global load (values from lsort via VALU)
template <int MODE>
__global__ __launch_bounds__(512) void gather_abl_kernel(
        const float* __restrict__ feat, const int* __restrict__ bcnt,
        const int* __restrict__ binned, float* __restrict__ out, int N) {
    __shared__ int lsort[EDGE_CAP];
    __shared__ int lbeg[NODES_PER_BKT + 1];
    __shared__ int lcur[NODES_PER_BKT];
    __shared__ int lcnt[NODES_PER_BKT];
    const int b = blockIdx.x;
    const int t = threadIdx.x;
    const size_t gbeg = (size_t)b * EDGE_CAP;
    const int cnt = min(bcnt[b], EDGE_CAP);
    const int node0 = b * NODES_PER_BKT;

    if (MODE == 0) {
        // ---- real sort: binned loads + LDS histogram ----
        if (t < NODES_PER_BKT) lcnt[t] = 0;
        __syncthreads();
        int p0 = -1, p1 = -1, p2 = -1, p3 = -1;
        if (t < cnt)        { p0 = binned[gbeg + t];        atomicAdd(&lcnt[(p0 >> 17) & 127], 1); }
        if (t + 512 < cnt)  { p1 = binned[gbeg + t + 512];  atomicAdd(&lcnt[(p1 >> 17) & 127], 1); }
        if (t + 1024 < cnt) { p2 = binned[gbeg + t + 1024]; atomicAdd(&lcnt[(p2 >> 17) & 127], 1); }
        if (t + 1536 < cnt) { p3 = binned[gbeg + t + 1536]; atomicAdd(&lcnt[(p3 >> 17) & 127], 1); }
        __syncthreads();
        if (t < 64) {
            const int a = lcnt[2 * t];
            const int c = lcnt[2 * t + 1];
            int s = a + c;
            for (int off = 1; off < 64; off <<= 1) {
                const int u = __shfl_up(s, off);
                if (t >= off) s += u;
            }
            const int ex = s - (a + c);
            lbeg[2 * t] = ex;         lcur[2 * t] = ex;
            lbeg[2 * t + 1] = ex + a; lcur[2 * t + 1] = ex + a;
            if (t == 63) lbeg[NODES_PER_BKT] = s;
        }
        __syncthreads();
        if (p0 >= 0) { const int r = atomicAdd(&lcur[(p0 >> 17) & 127], 1); lsort[r] = p0 & SRC_MASK; }
        if (p1 >= 0) { const int r = atomicAdd(&lcur[(p1 >> 17) & 127], 1); lsort[r] = p1 & SRC_MASK; }
        if (p2 >= 0) { const int r = atomicAdd(&lcur[(p2 >> 17) & 127], 1); lsort[r] = p2 & SRC_MASK; }
        if (p3 >= 0) { const int r = atomicAdd(&lcur[(p3 >> 17) & 127], 1); lsort[r] = p3 & SRC_MASK; }
        __syncthreads();
    } else {
        // ---- synthetic: uniform lbeg; lsort per MODE ----
        if (t <= NODES_PER_BKT) lbeg[t] = (t * cnt) >> NBKT_BITS;
        for (int i = t; i < cnt; i += 512) {
            int v;
            if (MODE == 3) {
                v = min(node0 + (i & 127), N - 1);  // block-local 32KB window
            } else {
                const unsigned h = (unsigned)i * 2654435761u + (unsigned)b * 40503u;
                v = (int)(((unsigned long long)h * (unsigned)N) >> 32);  // random
            }
            lsort[i] = v;
        }
        __syncthreads();
    }

    // ---- gather loop (identical code in all modes) ----
    const int wave = t >> 6;
    const int lane = t & 63;
    const int slot = lane >> 4;
    const int part = lane & 15;
    #pragma unroll
    for (int j = 0; j < NODES_PER_BKT / 8; ++j) {
        const int n = wave * (NODES_PER_BKT / 8) + j;
        const int e0 = lbeg[n];
        const int e1 = lbeg[n + 1];
        float4 acc = make_float4(0.f, 0.f, 0.f, 0.f);
        for (int k = e0 + slot; k < e1; k += 4) {
            const int s = lsort[k];
            float4 v;
            if (MODE == 4) {
                const float f = (float)(s ^ k);
                v = make_float4(f, f + 1.f, f + 2.f, f + 3.f);
            } else {
                v = *reinterpret_cast<const float4*>(feat + (size_t)s * 64 + part * 4);
            }
            acc.x += v.x; acc.y += v.y; acc.z += v.z; acc.w += v.w;
        }
        acc.x += __shfl_xor(acc.x, 16); acc.y += __shfl_xor(acc.y, 16);
        acc.z += __shfl_xor(acc.z, 16); acc.w += __shfl_xor(acc.w, 16);
        acc.x += __shfl_xor(acc.x, 32); acc.y += __shfl_xor(acc.y, 32);
        acc.z += __shfl_xor(acc.z, 32); acc.w += __shfl_xor(acc.w, 32);
        const int g = node0 + n;
        if (slot == 0 && g < N)
            *reinterpret_cast<float4*>(out + (size_t)g * 64 + part * 4) = acc;
    }
}

// ---------- last-resort fallback ----------
__global__ void atomic_fallback_kernel(const float* __restrict__ feat,
                                       const int* __restrict__ src,
                                       const int* __restrict__ dst,
                                       float* __restrict__ out, int E) {
    const int total = E * 16;
    int idx = blockIdx.x * blockDim.x + threadIdx.x;
    const int stride = gridDim.x * blockDim.x;
    for (int i = idx; i < total; i += stride) {
        const int e = i >> 4;
        const int part = i & 15;
        const float4 v = *reinterpret_cast<const float4*>(feat + (size_t)src[e] * 64 + part * 4);
        float* o = out + (size_t)dst[e] * 64 + part * 4;
        unsafeAtomicAdd(o + 0, v.x);
        unsafeAtomicAdd(o + 1, v.y);
        unsafeAtomicAdd(o + 2, v.z);
        unsafeAtomicAdd(o + 3, v.w);
    }
}

extern "C" void kernel_launch(void* const* d_in, const int* in_sizes, int n_in,
                              void* d_out, int out_size, void* d_ws, size_t ws_size,
                              hipStream_t stream) {
    const float* feat = (const float*)d_in[0];
    const int*   src  = (const int*)d_in[1];
    const int*   dst  = (const int*)d_in[2];
    float*       out  = (float*)d_out;
    const int E = in_sizes[1];
    const int N = out_size / 64;                          // 100000
    const int NB = (N + NODES_PER_BKT - 1) >> NBKT_BITS;  // 782
    const int binGrid = (E + BIN_CHUNK - 1) / BIN_CHUNK;  // 293

    const size_t need = ((size_t)NBKT_CAP + (size_t)NB * EDGE_CAP) * sizeof(int);
    const bool shape_ok = (NB <= NBKT_CAP) && (N <= SRC_MASK + 1);

    if (shape_ok && ws_size >= need) {
        int* bcnt   = (int*)d_ws;        // NBKT_CAP
        int* binned = bcnt + NBKT_CAP;   // NB * EDGE_CAP slots
        hipMemsetAsync(bcnt, 0, (size_t)NBKT_CAP * sizeof(int), stream);
        bin_direct_kernel<<<binGrid, 1024, 0, stream>>>(src, dst, bcnt, binned, E, NB);
        // Ablation probes (scratch d_out writes, overwritten by MODE 0):
        gather_abl_kernel<4><<<NB, 512, 0, stream>>>(feat, bcnt, binned, out, N);
        gather_abl_kernel<3><<<NB, 512, 0, stream>>>(feat, bcnt, binned, out, N);
        gather_abl_kernel<2><<<NB, 512, 0, stream>>>(feat, bcnt, binned, out, N);
        // Real kernel LAST: writes every d_out element.
        gather_abl_kernel<0><<<NB, 512, 0, stream>>>(feat, bcnt, binned, out, N);
    } else {
        hipMemsetAsync(out, 0, (size_t)out_size * sizeof(float), stream);
        int grid = (E * 16 + 255) / 256;
        if (grid > 4096) grid = 4096;
        atomic_fallback_kernel<<<grid, 256, 0, stream>>>(feat, src, dst, out, E);
    }
}

// Round 15
// 76.669 us; speedup vs baseline: 2.0512x; 2.0512x over previous
//
#include <hip/hip_runtime.h>

// h[v] = sum_{(u,v) in E} feat[u], feat: [N=100000,64] f32, E=1.2M.
// Round 15: r14 ablation verdict: 47us gather = serialized per-iteration
// dependent chain (ds_read -> lgkm -> vmem -> vmcnt), NOT the memory system
// (random-vs-L1 delta only ~12us). r9's MLP attempt failed because compiler
// allocated 32 VGPRs (occupancy-chasing) and re-serialized the streams.
// Fix: __launch_bounds__(512, 2) -> VGPR cap 256; 8 concurrent node-streams
// per wave (~110 VGPRs of live state: 8 accs, 8 loads in flight, 16 cursors).
// Occupancy drops to ~25% -- proven irrelevant (r7/r8/r11).

#define NBKT_BITS 7
#define NODES_PER_BKT 128      // 1 << NBKT_BITS
#define NBKT_CAP 1024
#define BIN_CHUNK 4096
#define SRC_MASK 0x1FFFF       // 17 bits, N=100000 < 131072
#define EDGE_CAP 2048          // per-bucket capacity; mean 1534, 13-sigma margin

// ---------- LDS-aggregated direct-slot bin (int4 reads) ----------
__global__ __launch_bounds__(1024) void bin_direct_kernel(
        const int* __restrict__ src, const int* __restrict__ dst,
        int* __restrict__ bcnt, int* __restrict__ binned, int E, int NB) {
    __shared__ int cnt[NBKT_CAP];
    __shared__ int base[NBKT_CAP];
    const int beg = blockIdx.x * BIN_CHUNK;
    const int end = min(E, beg + BIN_CHUNK);
    const int nE = end - beg;
    for (int i = threadIdx.x; i < NB; i += blockDim.x) cnt[i] = 0;
    __syncthreads();
    if ((nE & 3) == 0) {
        const int nv = nE >> 2;
        for (int i = threadIdx.x; i < nv; i += blockDim.x) {
            const int4 d4 = *reinterpret_cast<const int4*>(dst + beg + i * 4);
            atomicAdd(&cnt[d4.x >> NBKT_BITS], 1);
            atomicAdd(&cnt[d4.y >> NBKT_BITS], 1);
            atomicAdd(&cnt[d4.z >> NBKT_BITS], 1);
            atomicAdd(&cnt[d4.w >> NBKT_BITS], 1);
        }
    } else {
        for (int i = beg + threadIdx.x; i < end; i += blockDim.x)
            atomicAdd(&cnt[dst[i] >> NBKT_BITS], 1);
    }
    __syncthreads();
    for (int i = threadIdx.x; i < NB; i += blockDim.x) {
        const int c = cnt[i];
        base[i] = c ? atomicAdd(&bcnt[i], c) : 0;
        cnt[i] = 0;
    }
    __syncthreads();
    if ((nE & 3) == 0) {
        const int nv = nE >> 2;
        for (int i = threadIdx.x; i < nv; i += blockDim.x) {
            const int4 d4 = *reinterpret_cast<const int4*>(dst + beg + i * 4);
            const int4 s4 = *reinterpret_cast<const int4*>(src + beg + i * 4);
            {
                const int b = d4.x >> NBKT_BITS;
                const int r = atomicAdd(&cnt[b], 1);
                const int pos = base[b] + r;
                if (pos < EDGE_CAP)
                    binned[(size_t)b * EDGE_CAP + pos] = s4.x | ((d4.x & (NODES_PER_BKT - 1)) << 17);
            }
            {
                const int b = d4.y >> NBKT_BITS;
                const int r = atomicAdd(&cnt[b], 1);
                const int pos = base[b] + r;
                if (pos < EDGE_CAP)
                    binned[(size_t)b * EDGE_CAP + pos] = s4.y | ((d4.y & (NODES_PER_BKT - 1)) << 17);
            }
            {
                const int b = d4.z >> NBKT_BITS;
                const int r = atomicAdd(&cnt[b], 1);
                const int pos = base[b] + r;
                if (pos < EDGE_CAP)
                    binned[(size_t)b * EDGE_CAP + pos] = s4.z | ((d4.z & (NODES_PER_BKT - 1)) << 17);
            }
            {
                const int b = d4.w >> NBKT_BITS;
                const int r = atomicAdd(&cnt[b], 1);
                const int pos = base[b] + r;
                if (pos < EDGE_CAP)
                    binned[(size_t)b * EDGE_CAP + pos] = s4.w | ((d4.w & (NODES_PER_BKT - 1)) << 17);
            }
        }
    } else {
        for (int i = beg + threadIdx.x; i < end; i += blockDim.x) {
            const int d = dst[i];
            const int b = d >> NBKT_BITS;
            const int r = atomicAdd(&cnt[b], 1);
            const int pos = base[b] + r;
            if (pos < EDGE_CAP)
                binned[(size_t)b * EDGE_CAP + pos] = src[i] | ((d & (NODES_PER_BKT - 1)) << 17);
        }
    }
}

// ---------- fused LDS sort + 8-stream wide gather, 512 thr, VGPR-rich ------
__global__ __launch_bounds__(512, 2) void gather_kernel(
        const float* __restrict__ feat, const int* __restrict__ bcnt,
        const int* __restrict__ binned, float* __restrict__ out, int N) {
    __shared__ int lsort[EDGE_CAP];
    __shared__ int lbeg[NODES_PER_BKT + 1];
    __shared__ int lcur[NODES_PER_BKT];
    __shared__ int lcnt[NODES_PER_BKT];
    const int b = blockIdx.x;
    const int t = threadIdx.x;
    const size_t gbeg = (size_t)b * EDGE_CAP;
    const int cnt = min(bcnt[b], EDGE_CAP);

    if (t < NODES_PER_BKT) lcnt[t] = 0;
    __syncthreads();

    int p0 = -1, p1 = -1, p2 = -1, p3 = -1;
    if (t < cnt)        { p0 = binned[gbeg + t];        atomicAdd(&lcnt[(p0 >> 17) & 127], 1); }
    if (t + 512 < cnt)  { p1 = binned[gbeg + t + 512];  atomicAdd(&lcnt[(p1 >> 17) & 127], 1); }
    if (t + 1024 < cnt) { p2 = binned[gbeg + t + 1024]; atomicAdd(&lcnt[(p2 >> 17) & 127], 1); }
    if (t + 1536 < cnt) { p3 = binned[gbeg + t + 1536]; atomicAdd(&lcnt[(p3 >> 17) & 127], 1); }
    __syncthreads();

    if (t < 64) {
        const int a = lcnt[2 * t];
        const int c = lcnt[2 * t + 1];
        int s = a + c;
        for (int off = 1; off < 64; off <<= 1) {
            const int u = __shfl_up(s, off);
            if (t >= off) s += u;
        }
        const int ex = s - (a + c);
        lbeg[2 * t] = ex;         lcur[2 * t] = ex;
        lbeg[2 * t + 1] = ex + a; lcur[2 * t + 1] = ex + a;
        if (t == 63) lbeg[NODES_PER_BKT] = s;
    }
    __syncthreads();

    if (p0 >= 0) { const int r = atomicAdd(&lcur[(p0 >> 17) & 127], 1); lsort[r] = p0 & SRC_MASK; }
    if (p1 >= 0) { const int r = atomicAdd(&lcur[(p1 >> 17) & 127], 1); lsort[r] = p1 & SRC_MASK; }
    if (p2 >= 0) { const int r = atomicAdd(&lcur[(p2 >> 17) & 127], 1); lsort[r] = p2 & SRC_MASK; }
    if (p3 >= 0) { const int r = atomicAdd(&lcur[(p3 >> 17) & 127], 1); lsort[r] = p3 & SRC_MASK; }
    __syncthreads();

    // Gather: 8 waves x 16 nodes, processed as 2 groups of 8 CONCURRENT
    // streams. Per while-iteration: 8 independent lsort reads + 8 independent
    // float4 loads + 32 fmaf. ~110 VGPRs live; launch_bounds gives 256.
    const int wave = t >> 6;
    const int lane = t & 63;
    const int slot = lane >> 4;
    const int part = lane & 15;
    const int node0 = b * NODES_PER_BKT;
    #pragma unroll
    for (int g = 0; g < 2; ++g) {
        const int nb0 = wave * 16 + g * 8;
        int k0 = lbeg[nb0 + 0] + slot; const int e0 = lbeg[nb0 + 1];
        int k1 = lbeg[nb0 + 1] + slot; const int e1 = lbeg[nb0 + 2];
        int k2 = lbeg[nb0 + 2] + slot; const int e2 = lbeg[nb0 + 3];
        int k3 = lbeg[nb0 + 3] + slot; const int e3 = lbeg[nb0 + 4];
        int k4 = lbeg[nb0 + 4] + slot; const int e4 = lbeg[nb0 + 5];
        int k5 = lbeg[nb0 + 5] + slot; const int e5 = lbeg[nb0 + 6];
        int k6 = lbeg[nb0 + 6] + slot; const int e6 = lbeg[nb0 + 7];
        int k7 = lbeg[nb0 + 7] + slot; const int e7 = lbeg[nb0 + 8];
        float4 a0 = make_float4(0.f, 0.f, 0.f, 0.f);
        float4 a1 = make_float4(0.f, 0.f, 0.f, 0.f);
        float4 a2 = make_float4(0.f, 0.f, 0.f, 0.f);
        float4 a3 = make_float4(0.f, 0.f, 0.f, 0.f);
        float4 a4 = make_float4(0.f, 0.f, 0.f, 0.f);
        float4 a5 = make_float4(0.f, 0.f, 0.f, 0.f);
        float4 a6 = make_float4(0.f, 0.f, 0.f, 0.f);
        float4 a7 = make_float4(0.f, 0.f, 0.f, 0.f);
        while ((k0 < e0) | (k1 < e1) | (k2 < e2) | (k3 < e3) |
               (k4 < e4) | (k5 < e5) | (k6 < e6) | (k7 < e7)) {
            const bool c0 = k0 < e0, c1 = k1 < e1, c2 = k2 < e2, c3 = k3 < e3;
            const bool c4 = k4 < e4, c5 = k5 < e5, c6 = k6 < e6, c7 = k7 < e7;
            const int s0 = lsort[c0 ? k0 : 0];
            const int s1 = lsort[c1 ? k1 : 0];
            const int s2 = lsort[c2 ? k2 : 0];
            const int s3 = lsort[c3 ? k3 : 0];
            const int s4 = lsort[c4 ? k4 : 0];
            const int s5 = lsort[c5 ? k5 : 0];
            const int s6 = lsort[c6 ? k6 : 0];
            const int s7 = lsort[c7 ? k7 : 0];
            const float w0 = c0 ? 1.f : 0.f, w1 = c1 ? 1.f : 0.f;
            const float w2 = c2 ? 1.f : 0.f, w3 = c3 ? 1.f : 0.f;
            const float w4 = c4 ? 1.f : 0.f, w5 = c5 ? 1.f : 0.f;
            const float w6 = c6 ? 1.f : 0.f, w7 = c7 ? 1.f : 0.f;
            const float4 v0 = *reinterpret_cast<const float4*>(feat + (size_t)s0 * 64 + part * 4);
            const float4 v1 = *reinterpret_cast<const float4*>(feat + (size_t)s1 * 64 + part * 4);
            const float4 v2 = *reinterpret_cast<const float4*>(feat + (size_t)s2 * 64 + part * 4);
            const float4 v3 = *reinterpret_cast<const float4*>(feat + (size_t)s3 * 64 + part * 4);
            const float4 v4 = *reinterpret_cast<const float4*>(feat + (size_t)s4 * 64 + part * 4);
            const float4 v5 = *reinterpret_cast<const float4*>(feat + (size_t)s5 * 64 + part * 4);
            const float4 v6 = *reinterpret_cast<const float4*>(feat + (size_t)s6 * 64 + part * 4);
            const float4 v7 = *reinterpret_cast<const float4*>(feat + (size_t)s7 * 64 + part * 4);
            a0.x = fmaf(w0, v0.x, a0.x); a0.y = fmaf(w0, v0.y, a0.y);
            a0.z = fmaf(w0, v0.z, a0.z); a0.w = fmaf(w0, v0.w, a0.w);
            a1.x = fmaf(w1, v1.x, a1.x); a1.y = fmaf(w1, v1.y, a1.y);
            a1.z = fmaf(w1, v1.z, a1.z); a1.w = fmaf(w1, v1.w, a1.w);
            a2.x = fmaf(w2, v2.x, a2.x); a2.y = fmaf(w2, v2.y, a2.y);
            a2.z = fmaf(w2, v2.z, a2.z); a2.w = fmaf(w2, v2.w, a2.w);
            a3.x = fmaf(w3, v3.x, a3.x); a3.y = fmaf(w3, v3.y, a3.y);
            a3.z = fmaf(w3, v3.z, a3.z); a3.w = fmaf(w3, v3.w, a3.w);
            a4.x = fmaf(w4, v4.x, a4.x); a4.y = fmaf(w4, v4.y, a4.y);
            a4.z = fmaf(w4, v4.z, a4.z); a4.w = fmaf(w4, v4.w, a4.w);
            a5.x = fmaf(w5, v5.x, a5.x); a5.y = fmaf(w5, v5.y, a5.y);
            a5.z = fmaf(w5, v5.z, a5.z); a5.w = fmaf(w5, v5.w, a5.w);
            a6.x = fmaf(w6, v6.x, a6.x); a6.y = fmaf(w6, v6.y, a6.y);
            a6.z = fmaf(w6, v6.z, a6.z); a6.w = fmaf(w6, v6.w, a6.w);
            a7.x = fmaf(w7, v7.x, a7.x); a7.y = fmaf(w7, v7.y, a7.y);
            a7.z = fmaf(w7, v7.z, a7.z); a7.w = fmaf(w7, v7.w, a7.w);
            k0 += 4; k1 += 4; k2 += 4; k3 += 4;
            k4 += 4; k5 += 4; k6 += 4; k7 += 4;
        }
        // Cross-slot reduce (16-lane groups), then slot 0 stores.
        a0.x += __shfl_xor(a0.x, 16); a0.y += __shfl_xor(a0.y, 16);
        a0.z += __shfl_xor(a0.z, 16); a0.w += __shfl_xor(a0.w, 16);
        a0.x += __shfl_xor(a0.x, 32); a0.y += __shfl_xor(a0.y, 32);
        a0.z += __shfl_xor(a0.z, 32); a0.w += __shfl_xor(a0.w, 32);
        a1.x += __shfl_xor(a1.x, 16); a1.y += __shfl_xor(a1.y, 16);
        a1.z += __shfl_xor(a1.z, 16); a1.w += __shfl_xor(a1.w, 16);
        a1.x += __shfl_xor(a1.x, 32); a1.y += __shfl_xor(a1.y, 32);
        a1.z += __shfl_xor(a1.z, 32); a1.w += __shfl_xor(a1.w, 32);
        a2.x += __shfl_xor(a2.x, 16); a2.y += __shfl_xor(a2.y, 16);
        a2.z += __shfl_xor(a2.z, 16); a2.w += __shfl_xor(a2.w, 16);
        a2.x += __shfl_xor(a2.x, 32); a2.y += __shfl_xor(a2.y, 32);
        a2.z += __shfl_xor(a2.z, 32); a2.w += __shfl_xor(a2.w, 32);
        a3.x += __shfl_xor(a3.x, 16); a3.y += __shfl_xor(a3.y, 16);
        a3.z += __shfl_xor(a3.z, 16); a3.w += __shfl_xor(a3.w, 16);
        a3.x += __shfl_xor(a3.x, 32); a3.y += __shfl_xor(a3.y, 32);
        a3.z += __shfl_xor(a3.z, 32); a3.w += __shfl_xor(a3.w, 32);
        a4.x += __shfl_xor(a4.x, 16); a4.y += __shfl_xor(a4.y, 16);
        a4.z += __shfl_xor(a4.z, 16); a4.w += __shfl_xor(a4.w, 16);
        a4.x += __shfl_xor(a4.x, 32); a4.y += __shfl_xor(a4.y, 32);
        a4.z += __shfl_xor(a4.z, 32); a4.w += __shfl_xor(a4.w, 32);
        a5.x += __shfl_xor(a5.x, 16); a5.y += __shfl_xor(a5.y, 16);
        a5.z += __shfl_xor(a5.z, 16); a5.w += __shfl_xor(a5.w, 16);
        a5.x += __shfl_xor(a5.x, 32); a5.y += __shfl_xor(a5.y, 32);
        a5.z += __shfl_xor(a5.z, 32); a5.w += __shfl_xor(a5.w, 32);
        a6.x += __shfl_xor(a6.x, 16); a6.y += __shfl_xor(a6.y, 16);
        a6.z += __shfl_xor(a6.z, 16); a6.w += __shfl_xor(a6.w, 16);
        a6.x += __shfl_xor(a6.x, 32); a6.y += __shfl_xor(a6.y, 32);
        a6.z += __shfl_xor(a6.z, 32); a6.w += __shfl_xor(a6.w, 32);
        a7.x += __shfl_xor(a7.x, 16); a7.y += __shfl_xor(a7.y, 16);
        a7.z += __shfl_xor(a7.z, 16); a7.w += __shfl_xor(a7.w, 16);
        a7.x += __shfl_xor(a7.x, 32); a7.y += __shfl_xor(a7.y, 32);
        a7.z += __shfl_xor(a7.z, 32); a7.w += __shfl_xor(a7.w, 32);
        if (slot == 0) {
            const int g0 = node0 + nb0;
            if (g0 + 0 < N) *reinterpret_cast<float4*>(out + (size_t)(g0 + 0) * 64 + part * 4) = a0;
            if (g0 + 1 < N) *reinterpret_cast<float4*>(out + (size_t)(g0 + 1) * 64 + part * 4) = a1;
            if (g0 + 2 < N) *reinterpret_cast<float4*>(out + (size_t)(g0 + 2) * 64 + part * 4) = a2;
            if (g0 + 3 < N) *reinterpret_cast<float4*>(out + (size_t)(g0 + 3) * 64 + part * 4) = a3;
            if (g0 + 4 < N) *reinterpret_cast<float4*>(out + (size_t)(g0 + 4) * 64 + part * 4) = a4;
            if (g0 + 5 < N) *reinterpret_cast<float4*>(out + (size_t)(g0 + 5) * 64 + part * 4) = a5;
            if (g0 + 6 < N) *reinterpret_cast<float4*>(out + (size_t)(g0 + 6) * 64 + part * 4) = a6;
            if (g0 + 7 < N) *reinterpret_cast<float4*>(out + (size_t)(g0 + 7) * 64 + part * 4) = a7;
        }
    }
}

// ---------- last-resort fallback ----------
__global__ void atomic_fallback_kernel(const float* __restrict__ feat,
                                       const int* __restrict__ src,
                                       const int* __restrict__ dst,
                                       float* __restrict__ out, int E) {
    const int total = E * 16;
    int idx = blockIdx.x * blockDim.x + threadIdx.x;
    const int stride = gridDim.x * blockDim.x;
    for (int i = idx; i < total; i += stride) {
        const int e = i >> 4;
        const int part = i & 15;
        const float4 v = *reinterpret_cast<const float4*>(feat + (size_t)src[e] * 64 + part * 4);
        float* o = out + (size_t)dst[e] * 64 + part * 4;
        unsafeAtomicAdd(o + 0, v.x);
        unsafeAtomicAdd(o + 1, v.y);
        unsafeAtomicAdd(o + 2, v.z);
        unsafeAtomicAdd(o + 3, v.w);
    }
}

extern "C" void kernel_launch(void* const* d_in, const int* in_sizes, int n_in,
                              void* d_out, int out_size, void* d_ws, size_t ws_size,
                              hipStream_t stream) {
    const float* feat = (const float*)d_in[0];
    const int*   src  = (const int*)d_in[1];
    const int*   dst  = (const int*)d_in[2];
    float*       out  = (float*)d_out;
    const int E = in_sizes[1];
    const int N = out_size / 64;                          // 100000
    const int NB = (N + NODES_PER_BKT - 1) >> NBKT_BITS;  // 782
    const int binGrid = (E + BIN_CHUNK - 1) / BIN_CHUNK;  // 293

    const size_t need = ((size_t)NBKT_CAP + (size_t)NB * EDGE_CAP) * sizeof(int);
    const bool shape_ok = (NB <= NBKT_CAP) && (N <= SRC_MASK + 1);

    if (shape_ok && ws_size >= need) {
        int* bcnt   = (int*)d_ws;        // NBKT_CAP
        int* binned = bcnt + NBKT_CAP;   // NB * EDGE_CAP slots
        hipMemsetAsync(bcnt, 0, (size_t)NBKT_CAP * sizeof(int), stream);
        bin_direct_kernel<<<binGrid, 1024, 0, stream>>>(src, dst, bcnt, binned, E, NB);
        gather_kernel<<<NB, 512, 0, stream>>>(feat, bcnt, binned, out, N);
    } else {
        hipMemsetAsync(out, 0, (size_t)out_size * sizeof(float), stream);
        int grid = (E * 16 + 255) / 256;
        if (grid > 4096) grid = 4096;
        atomic_fallback_kernel<<<grid, 256, 0, stream>>>(feat, src, dst, out, E);
    }
}